// Round 1
// baseline (5191.428 us; speedup 1.0000x reference)
//
#include <hip/hip_runtime.h>
#include <math.h>

#define N_NODES 10000
#define N_EDGES 160000
#define F 128
#define F4 512

static constexpr float TWO_PI_OVER_L = 6.283185307179586f / 10.0f;

__device__ __forceinline__ float silu_f(float x) {
    return x / (1.0f + __expf(-x));
}

// layer1: 16 threads per row; thread c computes 8 outputs f0=c*8..+8 over K=128
__device__ __forceinline__ void layer1(const float xin[][F], float hout[][F],
                                       const float* __restrict__ w1,
                                       const float* __restrict__ b1,
                                       int e, int c)
{
    const int f0 = c * 8;
    float acc[8];
#pragma unroll
    for (int j = 0; j < 8; ++j) acc[j] = b1[f0 + j];
#pragma unroll 4
    for (int k = 0; k < F; ++k) {
        const float s = xin[e][k];
        const float4 wa = *(const float4*)&w1[k * F + f0];
        const float4 wb = *(const float4*)&w1[k * F + f0 + 4];
        acc[0] = fmaf(s, wa.x, acc[0]);
        acc[1] = fmaf(s, wa.y, acc[1]);
        acc[2] = fmaf(s, wa.z, acc[2]);
        acc[3] = fmaf(s, wa.w, acc[3]);
        acc[4] = fmaf(s, wb.x, acc[4]);
        acc[5] = fmaf(s, wb.y, acc[5]);
        acc[6] = fmaf(s, wb.z, acc[6]);
        acc[7] = fmaf(s, wb.w, acc[7]);
    }
#pragma unroll
    for (int j = 0; j < 8; ++j) hout[e][f0 + j] = silu_f(acc[j]);
}

// layer2: 16 threads per row; thread c accumulates 32 outputs f0=c*32..+32 over K=128
__device__ __forceinline__ void layer2_acc(const float hin[][F],
                                           const float* __restrict__ w2,
                                           const float* __restrict__ b2,
                                           int e, int c, float acc[32])
{
    const int f0 = c * 32;
#pragma unroll
    for (int j = 0; j < 32; ++j) acc[j] = b2[f0 + j];
    for (int k = 0; k < F; ++k) {
        const float s = hin[e][k];
        const float* wrow = &w2[k * F4 + f0];
#pragma unroll
        for (int j = 0; j < 32; j += 4) {
            const float4 w = *(const float4*)&wrow[j];
            acc[j + 0] = fmaf(s, w.x, acc[j + 0]);
            acc[j + 1] = fmaf(s, w.y, acc[j + 1]);
            acc[j + 2] = fmaf(s, w.z, acc[j + 2]);
            acc[j + 3] = fmaf(s, w.w, acc[j + 3]);
        }
    }
}

// phi MLP per node: block = 256 threads = 16 nodes
__global__ __launch_bounds__(256) void node_mlp_kernel(
    const float* __restrict__ inv,
    const float* __restrict__ w1, const float* __restrict__ b1,
    const float* __restrict__ w2, const float* __restrict__ b2,
    float* __restrict__ phi_out)
{
    __shared__ float s_x[16][F];
    __shared__ float s_h[16][F];
    const int t = threadIdx.x;
    const int n0 = blockIdx.x * 16;
    const int e = t >> 4, c = t & 15;
    {
        const float4* xp = (const float4*)&inv[(n0 + e) * F + c * 8];
        *(float4*)&s_x[e][c * 8]     = xp[0];
        *(float4*)&s_x[e][c * 8 + 4] = xp[1];
    }
    __syncthreads();
    layer1(s_x, s_h, w1, b1, e, c);
    __syncthreads();
    float acc[32];
    layer2_acc(s_h, w2, b2, e, c, acc);
    float* o = &phi_out[(n0 + e) * F4 + c * 32];
#pragma unroll
    for (int j = 0; j < 32; j += 4)
        *(float4*)&o[j] = make_float4(acc[j], acc[j + 1], acc[j + 2], acc[j + 3]);
}

template <bool PRECOMP>
__global__ __launch_bounds__(256) void edge_kernel(
    const int* __restrict__ ei, const float* __restrict__ dist,
    const float* __restrict__ dirv,
    const float* __restrict__ inv, const float* __restrict__ equiv,
    const float* __restrict__ ww1, const float* __restrict__ wb1,
    const float* __restrict__ ww2, const float* __restrict__ wb2,
    const float* __restrict__ pw1, const float* __restrict__ pb1,
    const float* __restrict__ pw2, const float* __restrict__ pb2,
    const float* __restrict__ phi_out,
    float* __restrict__ out_v, float* __restrict__ out_s)
{
    __shared__ float s_pe[16][F];
    __shared__ float s_h[16][F];
    __shared__ float s_m[16][F4];
    __shared__ float s_x[PRECOMP ? 1 : 16][F];
    __shared__ int   s_src[16], s_dst[16];
    __shared__ float s_dir[16][3], s_dist[16];

    const int t = threadIdx.x;
    const int e0 = blockIdx.x * 16;
    if (t < 16) {
        s_src[t]  = ei[e0 + t];
        s_dst[t]  = ei[N_EDGES + e0 + t];
        s_dist[t] = dist[e0 + t];
    } else if (t < 64) {
        const int i = t - 16;                      // 0..47
        s_dir[i / 3][i % 3] = dirv[e0 * 3 + i];
    }
    __syncthreads();
    const int e = t >> 4, c = t & 15;

    // positional encoding: interleaved sin/cos, ranks 1..64
    {
        const float d = s_dist[e] * TWO_PI_OVER_L;
#pragma unroll
        for (int kk = 0; kk < 4; ++kk) {
            const int k = c * 4 + kk;
            float sv, cv;
            sincosf(d * (float)(k + 1), &sv, &cv);
            s_pe[e][2 * k]     = sv;
            s_pe[e][2 * k + 1] = cv;
        }
    }
    if (!PRECOMP) {
        const float4* xp = (const float4*)&inv[s_src[e] * F + c * 8];
        *(float4*)&s_x[e][c * 8]     = xp[0];
        *(float4*)&s_x[e][c * 8 + 4] = xp[1];
    }
    __syncthreads();

    // w-path MLP
    layer1(s_pe, s_h, ww1, wb1, e, c);
    __syncthreads();
    {
        float acc[32];
        layer2_acc(s_h, ww2, wb2, e, c, acc);
        const int f0 = c * 32;
        if (PRECOMP) {
            const float* ph = &phi_out[s_src[e] * F4 + f0];
#pragma unroll
            for (int j = 0; j < 32; j += 4) {
                const float4 p = *(const float4*)&ph[j];
                s_m[e][f0 + j]     = acc[j]     * p.x;
                s_m[e][f0 + j + 1] = acc[j + 1] * p.y;
                s_m[e][f0 + j + 2] = acc[j + 2] * p.z;
                s_m[e][f0 + j + 3] = acc[j + 3] * p.w;
            }
        } else {
#pragma unroll
            for (int j = 0; j < 32; ++j) s_m[e][f0 + j] = acc[j];
        }
    }

    if (!PRECOMP) {
        __syncthreads();                 // all layer2-w reads of s_h done
        layer1(s_x, s_h, pw1, pb1, e, c);
        __syncthreads();
        float acc[32];
        layer2_acc(s_h, pw2, pb2, e, c, acc);
        const int f0 = c * 32;
#pragma unroll
        for (int j = 0; j < 32; ++j) s_m[e][f0 + j] *= acc[j];
    }
    __syncthreads();

    // epilogue: 16 edges x 128 features = 2048 pairs, 8 per thread
#pragma unroll
    for (int jj = 0; jj < 8; ++jj) {
        const int p  = t + jj * 256;
        const int ee = p >> 7, f = p & 127;
        const int src = s_src[ee], dst = s_dst[ee];
        const float g   = s_m[ee][f];
        const float cg  = s_m[ee][128 + f];
        const float sed = s_m[ee][256 + f];
        const float sf  = s_m[ee][384 + f];
        const float d0 = s_dir[ee][0], d1 = s_dir[ee][1], d2 = s_dir[ee][2];
        const float* es = &equiv[(src * F + f) * 3];
        const float* ed = &equiv[(dst * F + f) * 3];
        const float ax = es[0], ay = es[1], az = es[2];
        const float bx = ed[0], by = ed[1], bz = ed[2];
        const float cx = d1 * bz - d2 * by;
        const float cy = d2 * bx - d0 * bz;
        const float cz = d0 * by - d1 * bx;
        float* ov = &out_v[(dst * F + f) * 3];
        atomicAdd(&ov[0], fmaf(sed, d0, fmaf(g, ax, cg * cx)));
        atomicAdd(&ov[1], fmaf(sed, d1, fmaf(g, ay, cg * cy)));
        atomicAdd(&ov[2], fmaf(sed, d2, fmaf(g, az, cg * cz)));
        atomicAdd(&out_s[dst * F + f], sf * inv[src * F + f]);
    }
}

extern "C" void kernel_launch(void* const* d_in, const int* in_sizes, int n_in,
                              void* d_out, int out_size, void* d_ws, size_t ws_size,
                              hipStream_t stream)
{
    const int*   ei    = (const int*)d_in[0];
    const float* dist  = (const float*)d_in[1];
    const float* dirv  = (const float*)d_in[2];
    const float* inv   = (const float*)d_in[3];
    const float* equiv = (const float*)d_in[4];
    const float* pw1   = (const float*)d_in[5];
    const float* pb1   = (const float*)d_in[6];
    const float* pw2   = (const float*)d_in[7];
    const float* pb2   = (const float*)d_in[8];
    const float* ww1   = (const float*)d_in[9];
    const float* wb1   = (const float*)d_in[10];
    const float* ww2   = (const float*)d_in[11];
    const float* wb2   = (const float*)d_in[12];

    float* out_v = (float*)d_out;
    float* out_s = out_v + (size_t)N_NODES * F * 3;

    // initialize outputs with the residual base (atomics accumulate on top)
    hipMemcpyAsync(out_v, equiv, (size_t)N_NODES * F * 3 * sizeof(float),
                   hipMemcpyDeviceToDevice, stream);
    hipMemcpyAsync(out_s, inv, (size_t)N_NODES * F * sizeof(float),
                   hipMemcpyDeviceToDevice, stream);

    const size_t phi_bytes = (size_t)N_NODES * F4 * sizeof(float);
    if (ws_size >= phi_bytes) {
        float* phi_out = (float*)d_ws;
        node_mlp_kernel<<<N_NODES / 16, 256, 0, stream>>>(inv, pw1, pb1, pw2, pb2, phi_out);
        edge_kernel<true><<<N_EDGES / 16, 256, 0, stream>>>(
            ei, dist, dirv, inv, equiv, ww1, wb1, ww2, wb2,
            pw1, pb1, pw2, pb2, phi_out, out_v, out_s);
    } else {
        edge_kernel<false><<<N_EDGES / 16, 256, 0, stream>>>(
            ei, dist, dirv, inv, equiv, ww1, wb1, ww2, wb2,
            pw1, pb1, pw2, pb2, (const float*)nullptr, out_v, out_s);
    }
}